// Round 1
// baseline (319.258 us; speedup 1.0000x reference)
//
#include <hip/hip_runtime.h>
#include <stdint.h>

typedef __attribute__((ext_vector_type(4))) float floatx4;
typedef __attribute__((ext_vector_type(8))) short shortx8;
typedef __attribute__((ext_vector_type(2))) __bf16 bf16x2;

#define EPSF 1e-5f

#if defined(__has_builtin)
#if __has_builtin(__builtin_amdgcn_cvt_pk_bf16_f32)
#define HAVE_CVT_PK_BF16 1
#endif
#if __has_builtin(__builtin_amdgcn_rcpf)
#define HAVE_RCPF 1
#endif
#endif

// pack two fp32 -> packed bf16x2 (RNE)
__device__ __forceinline__ unsigned int pack2_bf16(float a, float b) {
#ifdef HAVE_CVT_PK_BF16
    bf16x2 r = __builtin_amdgcn_cvt_pk_bf16_f32(a, b);
    union { bf16x2 v; unsigned int u; } cv; cv.v = r; return cv.u;
#else
    unsigned int ua = __float_as_uint(a), ub = __float_as_uint(b);
    ua = (ua + 0x7fffu + ((ua >> 16) & 1u)) >> 16;
    ub = (ub + 0x7fffu + ((ub >> 16) & 1u)) & 0xffff0000u;
    return ub | ua;
#endif
}

__device__ __forceinline__ float fast_rcp(float x) {
#ifdef HAVE_RCPF
    return __builtin_amdgcn_rcpf(x);   // ~1 ulp, fine: output is bf16
#else
    return 1.0f / x;
#endif
}

// ---------------------------------------------------------------------------
// Phase 1: per-head M = (2+eps)*A^-1 - I,  A = (1+eps)I + (S_raw - S_raw^T).
// Branchless Gauss-Jordan (no pivoting; symmetric part (1+eps)I > 0).
// UNCHANGED (known-good).
// ---------------------------------------------------------------------------
__global__ __launch_bounds__(512) void cayley_invert(
    const float* __restrict__ S_raw, unsigned short* __restrict__ Mb)
{
    const int h  = blockIdx.x;
    const int t  = threadIdx.x;
    const int i  = t >> 2;      // row 0..127
    const int s  = t & 3;       // col segment 0..3
    const int j0 = s << 5;      // 32 cols per thread
    const float* Sr = S_raw + (size_t)h * 16384;

    float loc[32];
#pragma unroll
    for (int m = 0; m < 32; ++m) {
        const int j = j0 + m;
        float v = Sr[i * 128 + j] - Sr[j * 128 + i];
        if (j == i) v += 1.0f + EPSF;
        loc[m] = v;
    }

    __shared__ __align__(16) float rowbuf[2][128];
    __shared__ float dumbuf[2][128];

    if (i == 0) {
#pragma unroll
        for (int q = 0; q < 8; ++q) {
            floatx4 w;
            w[0] = loc[q*4+0]; w[1] = loc[q*4+1]; w[2] = loc[q*4+2]; w[3] = loc[q*4+3];
            if (q == 0 && s == 0) w[0] += 1.0f;
            *(floatx4*)(&rowbuf[0][j0 + q*4]) = w;
        }
    }
    if (s == 0) {
        float dv = loc[0];
        if (i == 0) dv -= 1.0f;
        dumbuf[0][i] = dv;
    }
    __syncthreads();

    for (int kb = 0; kb < 4; ++kb) {
#pragma unroll
        for (int kk = 0; kk < 32; ++kk) {
            const int cur = kk & 1;
            const int nxt = cur ^ 1;
            const int k   = (kb << 5) + kk;

            const float wk  = rowbuf[cur][k];
            const float dum = dumbuf[cur][i];
            const float akk = wk - 1.0f;
            const float de  = dum * fast_rcp(akk);

            floatx4 rv[8];
#pragma unroll
            for (int q = 0; q < 8; ++q)
                rv[q] = *(const floatx4*)(&rowbuf[cur][j0 + q*4]);

#pragma unroll
            for (int m = 0; m < 32; ++m)
                loc[m] = fmaf(-de, rv[m >> 2][m & 3], loc[m]);

            const int kn = k + 1;
            if (kn < 128) {
                const int sp   = (kk == 31) ? kb + 1 : kb;
                const int mloc = (kk == 31) ? 0 : kk + 1;
                const int qm   = mloc >> 2, em = mloc & 3;

                if (i == kn) {
#pragma unroll
                    for (int q = 0; q < 8; ++q) {
                        floatx4 w;
                        w[0] = loc[q*4+0]; w[1] = loc[q*4+1];
                        w[2] = loc[q*4+2]; w[3] = loc[q*4+3];
                        if (q == qm && s == sp) w[em] += 1.0f;
                        *(floatx4*)(&rowbuf[nxt][j0 + q*4]) = w;
                    }
                }
                if (s == sp) {
                    float dv = loc[mloc];
                    if (i == kn) dv -= 1.0f;
                    dumbuf[nxt][i] = dv;
                }
            }
            __syncthreads();
        }
    }

    unsigned short* dst = Mb + (size_t)h * 16384 + i * 128 + j0;
#pragma unroll
    for (int q = 0; q < 4; ++q) {
        union { shortx8 v; unsigned int u[4]; } cv;
#pragma unroll
        for (int p = 0; p < 4; ++p) {
            const int m = q*8 + p*2;
            const float v0 = (2.0f + EPSF) * loc[m]   - ((j0 + m   == i) ? 1.0f : 0.0f);
            const float v1 = (2.0f + EPSF) * loc[m+1] - ((j0 + m+1 == i) ? 1.0f : 0.0f);
            cv.u[p] = pack2_bf16(v0, v1);
        }
        *(shortx8*)(dst + q*8) = cv.v;
    }
}

// ---------------------------------------------------------------------------
// Phase 2 v4: y[n,:] = M_h @ x[n,:] per (b,h).  bf16 MFMA 16x16x32.
// Diagnosis of v3 (89.7us): MfmaUtil 3.6 / VALU 4.1 / HBM 28% / Occ 17.7%
// -> latency-bound at 2 waves/SIMD; VGPR=68 proves the xa[2][8] double
// buffer was compiler-defeated (needs >=96 live regs).
// Fix: trade ILP for TLP.
//  * 2048 blocks x 256 thr (wave = 32 rows = 2 tiles), launch_bounds(256,4)
//    -> 4 blocks/CU x 4 waves = 16 waves/CU (2.5x occupancy).
//  * LDS 52224 -> 32768 B: obuf dropped (acc lanes already hold 4
//    consecutive d for one n -> direct floatx4 stores, 64-B runs/row;
//    ct-pairs complete 128-B lines for L2 write combining).
//  * M staged FRAGMENT-MAJOR: chunk id c=(ct<<8|ks<<6|quad<<4|l15), so the
//    MFMA A-operand ds_read_b128 is base+lane*16 (linear, conflict-free);
//    v3's stride-136 layout was an 8-way bank conflict (2.6M cycles).
// ---------------------------------------------------------------------------
__global__ __launch_bounds__(256, 4) void cayley_apply(
    const float* __restrict__ x, const unsigned short* __restrict__ Mb,
    float* __restrict__ y)
{
    const int bid  = blockIdx.x;       // 2048 blocks
    const int bh   = bid >> 5;         // b*16+h, 0..63
    const int g    = bid & 31;         // 128-row group
    const int h    = bh & 15;
    const int tid  = threadIdx.x;
    const int w    = tid >> 6;
    const int lane = tid & 63;
    const int l15  = lane & 15;
    const int quad = lane >> 4;

    __shared__ __align__(16) unsigned short Msh[2048 * 8];   // 32768 B

    {   // stage M_h fragment-major: chunk c holds A-frag bytes for
        // (ct=c>>8, ks=(c>>6)&3, quad=(c>>4)&3, l15=c&15)
        const unsigned short* Mg = Mb + (size_t)h * 16384;
#pragma unroll
        for (int it = 0; it < 8; ++it) {
            const int c  = tid + it * 256;
            const int ct = c >> 8;
            const int ks = (c >> 6) & 3;
            const int qd = (c >> 4) & 3;
            const int r  = (ct << 4) | (c & 15);     // row = ct*16 + l15
            const int gq = (ks << 2) | qd;           // 16-B col chunk in row
            *(shortx8*)(&Msh[c * 8]) = *(const shortx8*)(Mg + r * 128 + gq * 8);
        }
    }
    __syncthreads();

    const size_t base = (size_t)bh * (4096 * 128);
    const int row0    = g * 128 + w * 32;            // wave's first row
    const float* xw   = x + base + (size_t)(row0 + l15) * 128 + quad * 8;

#pragma unroll
    for (int t = 0; t < 2; ++t) {
        const float* xt = xw + t * (16 * 128);

        floatx4 xa[8];
#pragma unroll
        for (int ks = 0; ks < 4; ++ks) {
            xa[ks*2+0] = *(const floatx4*)(xt + ks*32);
            xa[ks*2+1] = *(const floatx4*)(xt + ks*32 + 4);
        }

        shortx8 xf[4];
#pragma unroll
        for (int ks = 0; ks < 4; ++ks) {
            const floatx4 a = xa[ks*2+0];
            const floatx4 b = xa[ks*2+1];
            union { shortx8 v; unsigned int u[4]; } cv;
            cv.u[0] = pack2_bf16(a[0], a[1]);
            cv.u[1] = pack2_bf16(a[2], a[3]);
            cv.u[2] = pack2_bf16(b[0], b[1]);
            cv.u[3] = pack2_bf16(b[2], b[3]);
            xf[ks] = cv.v;
        }

        floatx4 acc[8];
#pragma unroll
        for (int ct = 0; ct < 8; ++ct) acc[ct] = (floatx4)0.0f;

#pragma unroll
        for (int ks = 0; ks < 4; ++ks) {
#pragma unroll
            for (int ct = 0; ct < 8; ++ct) {
                // linear wave read: addr = frag_base + lane*16  (conflict-free)
                const shortx8 mf = *(const shortx8*)(&Msh[((((ct << 2) | ks) << 6) | lane) * 8]);
                acc[ct] = __builtin_amdgcn_mfma_f32_16x16x32_bf16(mf, xf[ks], acc[ct], 0, 0, 0);
            }
        }

        // acc[ct] regs j=0..3 hold d = ct*16 + quad*4 + j for n = l15:
        // direct 16-B stores; per instruction 16 rows x contiguous 64 B.
        float* yt = y + base + (size_t)(row0 + t*16 + l15) * 128 + quad * 4;
#pragma unroll
        for (int ct = 0; ct < 8; ++ct)
            __builtin_nontemporal_store(acc[ct], (floatx4*)(yt + ct*16));
    }
}

extern "C" void kernel_launch(void* const* d_in, const int* in_sizes, int n_in,
                              void* d_out, int out_size, void* d_ws, size_t ws_size,
                              hipStream_t stream) {
    const float* x     = (const float*)d_in[0];   // (4,16,4096,128) fp32
    const float* S_raw = (const float*)d_in[1];   // (16,128,128) fp32
    float* y = (float*)d_out;                     // (4,16,4096,128) fp32
    unsigned short* Mb = (unsigned short*)d_ws;   // 16*128*128 bf16 = 512 KB

    cayley_invert<<<16, 512, 0, stream>>>(S_raw, Mb);
    cayley_apply<<<64 * 32, 256, 0, stream>>>(x, Mb, y);
}

// Round 2
// 305.327 us; speedup vs baseline: 1.0456x; 1.0456x over previous
//
#include <hip/hip_runtime.h>
#include <stdint.h>

typedef __attribute__((ext_vector_type(4))) float floatx4;
typedef __attribute__((ext_vector_type(8))) short shortx8;
typedef __attribute__((ext_vector_type(2))) __bf16 bf16x2;

#define EPSF 1e-5f

#if defined(__has_builtin)
#if __has_builtin(__builtin_amdgcn_cvt_pk_bf16_f32)
#define HAVE_CVT_PK_BF16 1
#endif
#if __has_builtin(__builtin_amdgcn_rcpf)
#define HAVE_RCPF 1
#endif
#endif

// pack two fp32 -> packed bf16x2 (RNE)
__device__ __forceinline__ unsigned int pack2_bf16(float a, float b) {
#ifdef HAVE_CVT_PK_BF16
    bf16x2 r = __builtin_amdgcn_cvt_pk_bf16_f32(a, b);
    union { bf16x2 v; unsigned int u; } cv; cv.v = r; return cv.u;
#else
    unsigned int ua = __float_as_uint(a), ub = __float_as_uint(b);
    ua = (ua + 0x7fffu + ((ua >> 16) & 1u)) >> 16;
    ub = (ub + 0x7fffu + ((ub >> 16) & 1u)) & 0xffff0000u;
    return ub | ua;
#endif
}

__device__ __forceinline__ float fast_rcp(float x) {
#ifdef HAVE_RCPF
    return __builtin_amdgcn_rcpf(x);   // ~1 ulp, fine: output is bf16
#else
    return 1.0f / x;
#endif
}

// ---------------------------------------------------------------------------
// Phase 1 v2: per-head M = (2+eps)*A^-1 - I,  A = (1+eps)I + (S_raw-S_raw^T).
// RANK-2 Gauss-Jordan: one barrier per pivot PAIR (64 barriers vs 128).
// Per step (pivots k,k+1) the block publishes:
//   w1buf = row k   with +1 baked at col k   (as before)
//   d1buf = col k   with -1 baked at row k   (as before)
//   r2buf = row k+1 RAW;  c2buf = col k+1 RAW
// and every thread locally composes both rank-1 updates:
//   e1 = d1_i/p1;  q = d1_{k+1}/p1;  r2'_j = r2_j - q*w1_j;  p2 = r2'_{k+1}
//   e2 = (c2_i - e1*w1_{k+1} - [i==k+1]) / p2
//   a''_ij = a_ij - e1*w1_j - e2*r2'_j  - e2*[j==k+1]
// Identical pivot sequence/stability as rank-1; ~3x VALU per step, half the
// barrier+LDS-roundtrip latency chain (which dominated: ~1670 cyc/step).
// ---------------------------------------------------------------------------
__global__ __launch_bounds__(512) void cayley_invert(
    const float* __restrict__ S_raw, unsigned short* __restrict__ Mb)
{
    const int h  = blockIdx.x;
    const int t  = threadIdx.x;
    const int i  = t >> 2;      // row 0..127
    const int s  = t & 3;       // col segment 0..3
    const int j0 = s << 5;      // 32 cols per thread
    const float* Sr = S_raw + (size_t)h * 16384;

    float loc[32];
#pragma unroll
    for (int m = 0; m < 32; ++m) {
        const int j = j0 + m;
        float v = Sr[i * 128 + j] - Sr[j * 128 + i];
        if (j == i) v += 1.0f + EPSF;
        loc[m] = v;
    }

    __shared__ __align__(16) float w1buf[2][128];
    __shared__ __align__(16) float r2buf[2][128];
    __shared__ float d1buf[2][128];
    __shared__ float c2buf[2][128];

    // initial publish for pivot pair (0,1)
    if (i == 0) {
#pragma unroll
        for (int q = 0; q < 8; ++q) {
            floatx4 w;
            w[0]=loc[q*4+0]; w[1]=loc[q*4+1]; w[2]=loc[q*4+2]; w[3]=loc[q*4+3];
            if (q == 0 && s == 0) w[0] += 1.0f;
            *(floatx4*)(&w1buf[0][j0 + q*4]) = w;
        }
    }
    if (i == 1) {
#pragma unroll
        for (int q = 0; q < 8; ++q) {
            floatx4 w;
            w[0]=loc[q*4+0]; w[1]=loc[q*4+1]; w[2]=loc[q*4+2]; w[3]=loc[q*4+3];
            *(floatx4*)(&r2buf[0][j0 + q*4]) = w;
        }
    }
    if (s == 0) {
        float dv = loc[0];
        if (i == 0) dv -= 1.0f;
        d1buf[0][i] = dv;
        c2buf[0][i] = loc[1];
    }
    __syncthreads();

    for (int kb = 0; kb < 4; ++kb) {
#pragma unroll
        for (int kk = 0; kk < 16; ++kk) {         // 16 pivot-pairs per kb
            const int cur = kk & 1;
            const int nxt = cur ^ 1;
            const int k   = (kb << 5) + (kk << 1);

            const float w1k  = w1buf[cur][k];           // a_kk + 1
            const float rp1  = fast_rcp(w1k - 1.0f);    // 1/p1
            const float e1   = d1buf[cur][i] * rp1;
            const float qc   = d1buf[cur][k + 1] * rp1; // a_{k+1,k}/p1
            const float w1k1 = w1buf[cur][k + 1];       // a_{k,k+1}
            const float p2   = r2buf[cur][k + 1] - qc * w1k1;
            const float rp2  = fast_rcp(p2);
            const float c2p  = c2buf[cur][i] - e1 * w1k1;  // a'_{i,k+1}
            const float e2   = (c2p - ((i == k + 1) ? 1.0f : 0.0f)) * rp2;

            floatx4 w1v[8], r2v[8];
#pragma unroll
            for (int q = 0; q < 8; ++q) {
                w1v[q] = *(const floatx4*)(&w1buf[cur][j0 + q*4]);
                r2v[q] = *(const floatx4*)(&r2buf[cur][j0 + q*4]);
            }
#pragma unroll
            for (int m = 0; m < 32; ++m) {
                const float w1m = w1v[m >> 2][m & 3];
                const float r2p = fmaf(-qc, w1m, r2v[m >> 2][m & 3]); // w2 sans delta
                loc[m] = fmaf(-e2, r2p, fmaf(-e1, w1m, loc[m]));
            }
            if (s == kb) loc[(kk << 1) + 1] -= e2;   // delta fix at col k+1

            const int kn = k + 2;
            if (kn < 128) {
                const int sp = (kk == 15) ? kb + 1 : kb;
                const int m2 = (kk == 15) ? 0 : (kk << 1) + 2;  // col k+2 pos
                const int m3 = m2 + 1;                          // col k+3 pos
                const int q2 = m2 >> 2, f2 = m2 & 3;

                if (i == kn) {          // publish w1 = row k+2 (+1 at col k+2)
#pragma unroll
                    for (int q = 0; q < 8; ++q) {
                        floatx4 w;
                        w[0]=loc[q*4+0]; w[1]=loc[q*4+1]; w[2]=loc[q*4+2]; w[3]=loc[q*4+3];
                        if (q == q2 && s == sp) w[f2] += 1.0f;
                        *(floatx4*)(&w1buf[nxt][j0 + q*4]) = w;
                    }
                }
                if (i == kn + 1) {      // publish r2 = row k+3 raw
#pragma unroll
                    for (int q = 0; q < 8; ++q) {
                        floatx4 w;
                        w[0]=loc[q*4+0]; w[1]=loc[q*4+1]; w[2]=loc[q*4+2]; w[3]=loc[q*4+3];
                        *(floatx4*)(&r2buf[nxt][j0 + q*4]) = w;
                    }
                }
                if (s == sp) {
                    float dv = loc[m2];
                    if (i == kn) dv -= 1.0f;
                    d1buf[nxt][i] = dv;     // col k+2, -1 baked at row k+2
                    c2buf[nxt][i] = loc[m3];// col k+3 raw
                }
            }
            __syncthreads();
        }
    }

    unsigned short* dst = Mb + (size_t)h * 16384 + i * 128 + j0;
#pragma unroll
    for (int q = 0; q < 4; ++q) {
        union { shortx8 v; unsigned int u[4]; } cv;
#pragma unroll
        for (int p = 0; p < 4; ++p) {
            const int m = q*8 + p*2;
            const float v0 = (2.0f + EPSF) * loc[m]   - ((j0 + m   == i) ? 1.0f : 0.0f);
            const float v1 = (2.0f + EPSF) * loc[m+1] - ((j0 + m+1 == i) ? 1.0f : 0.0f);
            cv.u[p] = pack2_bf16(v0, v1);
        }
        *(shortx8*)(dst + q*8) = cv.v;
    }
}

// ---------------------------------------------------------------------------
// Phase 2 v5: y[n,:] = M_h @ x[n,:].  Diagnosis of v4 (92us): occupancy
// doubled, conflicts 0, yet BW flat at 2.4 TB/s and all pipes <5% busy ->
// waves parked on s_waitcnt.  Theory: vmcnt counts STORES; nontemporal
// (no-allocate) stores must complete at HBM, so each tile's pack waited on
// the previous tile's NT stores draining (~us under congestion).  Evidence:
// WRITE_SIZE 150MB vs 134MB ideal (partial-line NT amplification), and v3
// (also NT) plateaued identically.
// Fix: plain stores (complete at L2 ack, async writeback) + hoist both
// tiles' loads up front (16 loads in flight/wave; VGPR ~115 <= 128 budget).
// Fragment-major M staging + direct acc stores kept from v4.
// ---------------------------------------------------------------------------
__global__ __launch_bounds__(256, 4) void cayley_apply(
    const float* __restrict__ x, const unsigned short* __restrict__ Mb,
    float* __restrict__ y)
{
    const int bid  = blockIdx.x;       // 2048 blocks
    const int bh   = bid >> 5;         // b*16+h, 0..63
    const int g    = bid & 31;         // 128-row group
    const int h    = bh & 15;
    const int tid  = threadIdx.x;
    const int w    = tid >> 6;
    const int lane = tid & 63;
    const int l15  = lane & 15;
    const int quad = lane >> 4;

    __shared__ __align__(16) unsigned short Msh[2048 * 8];   // 32768 B

    {   // stage M_h fragment-major: chunk c holds A-frag bytes for
        // (ct=c>>8, ks=(c>>6)&3, quad=(c>>4)&3, l15=c&15)
        const unsigned short* Mg = Mb + (size_t)h * 16384;
#pragma unroll
        for (int it = 0; it < 8; ++it) {
            const int c  = tid + it * 256;
            const int ct = c >> 8;
            const int ks = (c >> 6) & 3;
            const int qd = (c >> 4) & 3;
            const int r  = (ct << 4) | (c & 15);     // row = ct*16 + l15
            const int gq = (ks << 2) | qd;           // 16-B col chunk in row
            *(shortx8*)(&Msh[c * 8]) = *(const shortx8*)(Mg + r * 128 + gq * 8);
        }
    }
    __syncthreads();

    const size_t base = (size_t)bh * (4096 * 128);
    const int row0    = g * 128 + w * 32;            // wave's first row
    const float* xw   = x + base + (size_t)(row0 + l15) * 128 + quad * 8;

    // load BOTH 16-row tiles up front: 16 global loads in flight per wave
    floatx4 xa[2][8];
#pragma unroll
    for (int t = 0; t < 2; ++t) {
#pragma unroll
        for (int ks = 0; ks < 4; ++ks) {
            xa[t][ks*2+0] = *(const floatx4*)(xw + t*2048 + ks*32);
            xa[t][ks*2+1] = *(const floatx4*)(xw + t*2048 + ks*32 + 4);
        }
    }

#pragma unroll
    for (int t = 0; t < 2; ++t) {
        shortx8 xf[4];
#pragma unroll
        for (int ks = 0; ks < 4; ++ks) {
            const floatx4 a = xa[t][ks*2+0];
            const floatx4 b = xa[t][ks*2+1];
            union { shortx8 v; unsigned int u[4]; } cv;
            cv.u[0] = pack2_bf16(a[0], a[1]);
            cv.u[1] = pack2_bf16(a[2], a[3]);
            cv.u[2] = pack2_bf16(b[0], b[1]);
            cv.u[3] = pack2_bf16(b[2], b[3]);
            xf[ks] = cv.v;
        }

        floatx4 acc[8];
#pragma unroll
        for (int ct = 0; ct < 8; ++ct) acc[ct] = (floatx4)0.0f;

#pragma unroll
        for (int ks = 0; ks < 4; ++ks) {
#pragma unroll
            for (int ct = 0; ct < 8; ++ct) {
                // linear wave read: addr = frag_base + lane*16 (conflict-free)
                const shortx8 mf = *(const shortx8*)(&Msh[((((ct << 2) | ks) << 6) | lane) * 8]);
                acc[ct] = __builtin_amdgcn_mfma_f32_16x16x32_bf16(mf, xf[ks], acc[ct], 0, 0, 0);
            }
        }

        // acc[ct] regs j=0..3 hold d = ct*16 + quad*4 + j for n = l15:
        // plain stores (complete at L2; ct-pairs complete 128-B lines)
        float* yt = y + base + (size_t)(row0 + t*16 + l15) * 128 + quad * 4;
#pragma unroll
        for (int ct = 0; ct < 8; ++ct)
            *(floatx4*)(yt + ct*16) = acc[ct];
    }
}

extern "C" void kernel_launch(void* const* d_in, const int* in_sizes, int n_in,
                              void* d_out, int out_size, void* d_ws, size_t ws_size,
                              hipStream_t stream) {
    const float* x     = (const float*)d_in[0];   // (4,16,4096,128) fp32
    const float* S_raw = (const float*)d_in[1];   // (16,128,128) fp32
    float* y = (float*)d_out;                     // (4,16,4096,128) fp32
    unsigned short* Mb = (unsigned short*)d_ws;   // 16*128*128 bf16 = 512 KB

    cayley_invert<<<16, 512, 0, stream>>>(S_raw, Mb);
    cayley_apply<<<64 * 32, 256, 0, stream>>>(x, Mb, y);
}

// Round 3
// 303.059 us; speedup vs baseline: 1.0535x; 1.0075x over previous
//
#include <hip/hip_runtime.h>
#include <stdint.h>

typedef __attribute__((ext_vector_type(4))) float floatx4;
typedef __attribute__((ext_vector_type(8))) short shortx8;
typedef __attribute__((ext_vector_type(2))) unsigned int uintx2;
typedef __attribute__((ext_vector_type(2))) __bf16 bf16x2;

#define EPSF 1e-5f

#if defined(__has_builtin)
#if __has_builtin(__builtin_amdgcn_cvt_pk_bf16_f32)
#define HAVE_CVT_PK_BF16 1
#endif
#if __has_builtin(__builtin_amdgcn_rcpf)
#define HAVE_RCPF 1
#endif
#endif

// pack two fp32 -> packed bf16x2 (RNE)
__device__ __forceinline__ unsigned int pack2_bf16(float a, float b) {
#ifdef HAVE_CVT_PK_BF16
    bf16x2 r = __builtin_amdgcn_cvt_pk_bf16_f32(a, b);
    union { bf16x2 v; unsigned int u; } cv; cv.v = r; return cv.u;
#else
    unsigned int ua = __float_as_uint(a), ub = __float_as_uint(b);
    ua = (ua + 0x7fffu + ((ua >> 16) & 1u)) >> 16;
    ub = (ub + 0x7fffu + ((ub >> 16) & 1u)) & 0xffff0000u;
    return ub | ua;
#endif
}

__device__ __forceinline__ float fast_rcp(float x) {
#ifdef HAVE_RCPF
    return __builtin_amdgcn_rcpf(x);   // ~1 ulp, fine: output is bf16
#else
    return 1.0f / x;
#endif
}

// ---------------------------------------------------------------------------
// Phase 1 v2: per-head M = (2+eps)*A^-1 - I,  A = (1+eps)I + (S_raw-S_raw^T).
// RANK-2 Gauss-Jordan (64 barriers).  UNCHANGED from round 2 (passed).
// ---------------------------------------------------------------------------
__global__ __launch_bounds__(512) void cayley_invert(
    const float* __restrict__ S_raw, unsigned short* __restrict__ Mb)
{
    const int h  = blockIdx.x;
    const int t  = threadIdx.x;
    const int i  = t >> 2;      // row 0..127
    const int s  = t & 3;       // col segment 0..3
    const int j0 = s << 5;      // 32 cols per thread
    const float* Sr = S_raw + (size_t)h * 16384;

    float loc[32];
#pragma unroll
    for (int m = 0; m < 32; ++m) {
        const int j = j0 + m;
        float v = Sr[i * 128 + j] - Sr[j * 128 + i];
        if (j == i) v += 1.0f + EPSF;
        loc[m] = v;
    }

    __shared__ __align__(16) float w1buf[2][128];
    __shared__ __align__(16) float r2buf[2][128];
    __shared__ float d1buf[2][128];
    __shared__ float c2buf[2][128];

    // initial publish for pivot pair (0,1)
    if (i == 0) {
#pragma unroll
        for (int q = 0; q < 8; ++q) {
            floatx4 w;
            w[0]=loc[q*4+0]; w[1]=loc[q*4+1]; w[2]=loc[q*4+2]; w[3]=loc[q*4+3];
            if (q == 0 && s == 0) w[0] += 1.0f;
            *(floatx4*)(&w1buf[0][j0 + q*4]) = w;
        }
    }
    if (i == 1) {
#pragma unroll
        for (int q = 0; q < 8; ++q) {
            floatx4 w;
            w[0]=loc[q*4+0]; w[1]=loc[q*4+1]; w[2]=loc[q*4+2]; w[3]=loc[q*4+3];
            *(floatx4*)(&r2buf[0][j0 + q*4]) = w;
        }
    }
    if (s == 0) {
        float dv = loc[0];
        if (i == 0) dv -= 1.0f;
        d1buf[0][i] = dv;
        c2buf[0][i] = loc[1];
    }
    __syncthreads();

    for (int kb = 0; kb < 4; ++kb) {
#pragma unroll
        for (int kk = 0; kk < 16; ++kk) {         // 16 pivot-pairs per kb
            const int cur = kk & 1;
            const int nxt = cur ^ 1;
            const int k   = (kb << 5) + (kk << 1);

            const float w1k  = w1buf[cur][k];           // a_kk + 1
            const float rp1  = fast_rcp(w1k - 1.0f);    // 1/p1
            const float e1   = d1buf[cur][i] * rp1;
            const float qc   = d1buf[cur][k + 1] * rp1; // a_{k+1,k}/p1
            const float w1k1 = w1buf[cur][k + 1];       // a_{k,k+1}
            const float p2   = r2buf[cur][k + 1] - qc * w1k1;
            const float rp2  = fast_rcp(p2);
            const float c2p  = c2buf[cur][i] - e1 * w1k1;  // a'_{i,k+1}
            const float e2   = (c2p - ((i == k + 1) ? 1.0f : 0.0f)) * rp2;

            floatx4 w1v[8], r2v[8];
#pragma unroll
            for (int q = 0; q < 8; ++q) {
                w1v[q] = *(const floatx4*)(&w1buf[cur][j0 + q*4]);
                r2v[q] = *(const floatx4*)(&r2buf[cur][j0 + q*4]);
            }
#pragma unroll
            for (int m = 0; m < 32; ++m) {
                const float w1m = w1v[m >> 2][m & 3];
                const float r2p = fmaf(-qc, w1m, r2v[m >> 2][m & 3]); // w2 sans delta
                loc[m] = fmaf(-e2, r2p, fmaf(-e1, w1m, loc[m]));
            }
            if (s == kb) loc[(kk << 1) + 1] -= e2;   // delta fix at col k+1

            const int kn = k + 2;
            if (kn < 128) {
                const int sp = (kk == 15) ? kb + 1 : kb;
                const int m2 = (kk == 15) ? 0 : (kk << 1) + 2;  // col k+2 pos
                const int m3 = m2 + 1;                          // col k+3 pos
                const int q2 = m2 >> 2, f2 = m2 & 3;

                if (i == kn) {          // publish w1 = row k+2 (+1 at col k+2)
#pragma unroll
                    for (int q = 0; q < 8; ++q) {
                        floatx4 w;
                        w[0]=loc[q*4+0]; w[1]=loc[q*4+1]; w[2]=loc[q*4+2]; w[3]=loc[q*4+3];
                        if (q == q2 && s == sp) w[f2] += 1.0f;
                        *(floatx4*)(&w1buf[nxt][j0 + q*4]) = w;
                    }
                }
                if (i == kn + 1) {      // publish r2 = row k+3 raw
#pragma unroll
                    for (int q = 0; q < 8; ++q) {
                        floatx4 w;
                        w[0]=loc[q*4+0]; w[1]=loc[q*4+1]; w[2]=loc[q*4+2]; w[3]=loc[q*4+3];
                        *(floatx4*)(&r2buf[nxt][j0 + q*4]) = w;
                    }
                }
                if (s == sp) {
                    float dv = loc[m2];
                    if (i == kn) dv -= 1.0f;
                    d1buf[nxt][i] = dv;     // col k+2, -1 baked at row k+2
                    c2buf[nxt][i] = loc[m3];// col k+3 raw
                }
            }
            __syncthreads();
        }
    }

    unsigned short* dst = Mb + (size_t)h * 16384 + i * 128 + j0;
#pragma unroll
    for (int q = 0; q < 4; ++q) {
        union { shortx8 v; unsigned int u[4]; } cv;
#pragma unroll
        for (int p = 0; p < 4; ++p) {
            const int m = q*8 + p*2;
            const float v0 = (2.0f + EPSF) * loc[m]   - ((j0 + m   == i) ? 1.0f : 0.0f);
            const float v1 = (2.0f + EPSF) * loc[m+1] - ((j0 + m+1 == i) ? 1.0f : 0.0f);
            cv.u[p] = pack2_bf16(v0, v1);
        }
        *(shortx8*)(dst + q*8) = cv.v;
    }
}

// ---------------------------------------------------------------------------
// Phase 2 v6: y[n,:] = M_h @ x[n,:].  Diagnosis of v5 (88us): dur invariant
// across NT/plain stores, 512/2048 blocks, and even HBM-vs-L3 x sourcing
// (one pass: 134MB HBM, same 87us) -> NOT HBM-BW-bound.  The invariant is
// the x READ pattern: every load instr touched 16 cache lines at 512B
// stride using 64B of each (half-line sectors).  Reads hold L1 MSHR slots
// until fill; at ~64 slots/CU x 64B that caps in-flight reads at ~4KB/CU
// -> 256CU/375ns = ~2.7 TB/s = the observed wall.  (Copy bench's 6.3 TB/s
// uses full 128B lines: same slots, 2x bytes.  Stores ack at L2 and don't
// hold MSHRs -- why v3-full-line vs v4-half-line stores were identical.)
// Fix: line-contiguous x loads (each instr = 2 full rows = 8 full lines,
// lane>>5 = row, (lane&31)*16B in-row) + per-wave LDS transpose to frag
// order.  bf16 convert in regs, ds_write 8B swizzled (^(row&7)<<4),
// frag ds_read_b128 with same swizzle (8 lanes/16B-group = b128 floor).
// sched_barrier(0) pins the 8-load batch (compiler kept re-serializing).
// LDS 48KB -> 3 blocks/CU = 12 waves: enough to keep MSHRs full.
// ---------------------------------------------------------------------------
__global__ __launch_bounds__(256, 3) void cayley_apply(
    const float* __restrict__ x, const unsigned short* __restrict__ Mb,
    float* __restrict__ y)
{
    const int bid  = blockIdx.x;       // 2048 blocks
    const int bh   = bid >> 5;         // b*16+h, 0..63
    const int g    = bid & 31;         // 128-row group
    const int h    = bh & 15;
    const int tid  = threadIdx.x;
    const int w    = tid >> 6;
    const int lane = tid & 63;
    const int l15  = lane & 15;
    const int quad = lane >> 4;

    __shared__ __align__(16) unsigned short Msh[2048 * 8];   // 32768 B
    __shared__ __align__(16) unsigned char  xls[4][4096];    // 16384 B

    {   // stage M_h fragment-major: chunk c holds A-frag bytes for
        // (ct=c>>8, ks=(c>>6)&3, quad=(c>>4)&3, l15=c&15)
        const unsigned short* Mg = Mb + (size_t)h * 16384;
#pragma unroll
        for (int it = 0; it < 8; ++it) {
            const int c  = tid + it * 256;
            const int ct = c >> 8;
            const int ks = (c >> 6) & 3;
            const int qd = (c >> 4) & 3;
            const int r  = (ct << 4) | (c & 15);     // row = ct*16 + l15
            const int gq = (ks << 2) | qd;           // 16-B col chunk in row
            *(shortx8*)(&Msh[c * 8]) = *(const shortx8*)(Mg + r * 128 + gq * 8);
        }
    }
    __syncthreads();

    const size_t base = (size_t)bh * (4096 * 128);
    const int row0    = g * 128 + w * 32;            // wave's first row
    const int lrow    = lane >> 5;                   // 0..1: row within pair
    const int lcol    = (lane & 31) * 4;             // float idx within row
    const float* xw   = x + base + (size_t)(row0 + lrow) * 128 + lcol;

    unsigned char* xb = xls[w];                      // per-wave 4KB buffer
    // frag-read addresses are loop-invariant per lane
    const unsigned int rb0 = (unsigned int)l15 * 256 + (unsigned int)quad * 16;
    const unsigned int rsw = ((unsigned int)(l15 & 7)) << 4;

#pragma unroll
    for (int t = 0; t < 2; ++t) {
        const float* xt = xw + (size_t)(t * 16) * 128;

        // 8 line-contiguous loads: instr i covers rows 2i..2i+1 fully
        floatx4 xr[8];
#pragma unroll
        for (int i = 0; i < 8; ++i)
            xr[i] = *(const floatx4*)(xt + (size_t)(2 * i) * 128);
        __builtin_amdgcn_sched_barrier(0);   // keep the 8 loads batched

        // convert + swizzled LDS write (lane owns row 2i+lrow, bytes lcol*2..+8)
#pragma unroll
        for (int i = 0; i < 8; ++i) {
            const int row = 2 * i + lrow;
            const unsigned int a =
                ((unsigned int)row * 256 + (unsigned int)lcol * 2)
                ^ (((unsigned int)(row & 7)) << 4);
            uintx2 p;
            p[0] = pack2_bf16(xr[i][0], xr[i][1]);
            p[1] = pack2_bf16(xr[i][2], xr[i][3]);
            *(uintx2*)(xb + a) = p;
        }

        // same-wave DS ordering: drain writes before frag reads
        asm volatile("s_waitcnt lgkmcnt(0)" ::: "memory");
        __builtin_amdgcn_sched_barrier(0);

        shortx8 xf[4];
#pragma unroll
        for (int ks = 0; ks < 4; ++ks)
            xf[ks] = *(const shortx8*)(xb + ((rb0 + (unsigned int)ks * 64) ^ rsw));

        floatx4 acc[8];
#pragma unroll
        for (int ct = 0; ct < 8; ++ct) acc[ct] = (floatx4)0.0f;

#pragma unroll
        for (int ks = 0; ks < 4; ++ks) {
#pragma unroll
            for (int ct = 0; ct < 8; ++ct) {
                // linear wave read: addr = frag_base + lane*16 (conflict-free)
                const shortx8 mf = *(const shortx8*)(&Msh[((((ct << 2) | ks) << 6) | lane) * 8]);
                acc[ct] = __builtin_amdgcn_mfma_f32_16x16x32_bf16(mf, xf[ks], acc[ct], 0, 0, 0);
            }
        }

        // acc[ct] regs j=0..3 hold d = ct*16 + quad*4 + j for n = l15
        float* yt = y + base + (size_t)(row0 + t*16 + l15) * 128 + quad * 4;
#pragma unroll
        for (int ct = 0; ct < 8; ++ct)
            *(floatx4*)(yt + ct*16) = acc[ct];
    }
}

extern "C" void kernel_launch(void* const* d_in, const int* in_sizes, int n_in,
                              void* d_out, int out_size, void* d_ws, size_t ws_size,
                              hipStream_t stream) {
    const float* x     = (const float*)d_in[0];   // (4,16,4096,128) fp32
    const float* S_raw = (const float*)d_in[1];   // (16,128,128) fp32
    float* y = (float*)d_out;                     // (4,16,4096,128) fp32
    unsigned short* Mb = (unsigned short*)d_ws;   // 16*128*128 bf16 = 512 KB

    cayley_invert<<<16, 512, 0, stream>>>(S_raw, Mb);
    cayley_apply<<<64 * 32, 256, 0, stream>>>(x, Mb, y);
}

// Round 4
// 302.846 us; speedup vs baseline: 1.0542x; 1.0007x over previous
//
#include <hip/hip_runtime.h>
#include <stdint.h>

typedef __attribute__((ext_vector_type(4))) float floatx4;
typedef __attribute__((ext_vector_type(8))) short shortx8;
typedef __attribute__((ext_vector_type(2))) unsigned int uintx2;
typedef __attribute__((ext_vector_type(2))) __bf16 bf16x2;

#define EPSF 1e-5f

#if defined(__has_builtin)
#if __has_builtin(__builtin_amdgcn_cvt_pk_bf16_f32)
#define HAVE_CVT_PK_BF16 1
#endif
#if __has_builtin(__builtin_amdgcn_rcpf)
#define HAVE_RCPF 1
#endif
#endif

// pack two fp32 -> packed bf16x2 (RNE)
__device__ __forceinline__ unsigned int pack2_bf16(float a, float b) {
#ifdef HAVE_CVT_PK_BF16
    bf16x2 r = __builtin_amdgcn_cvt_pk_bf16_f32(a, b);
    union { bf16x2 v; unsigned int u; } cv; cv.v = r; return cv.u;
#else
    unsigned int ua = __float_as_uint(a), ub = __float_as_uint(b);
    ua = (ua + 0x7fffu + ((ua >> 16) & 1u)) >> 16;
    ub = (ub + 0x7fffu + ((ub >> 16) & 1u)) & 0xffff0000u;
    return ub | ua;
#endif
}

__device__ __forceinline__ float fast_rcp(float x) {
#ifdef HAVE_RCPF
    return __builtin_amdgcn_rcpf(x);   // ~1 ulp, fine: output is bf16
#else
    return 1.0f / x;
#endif
}

// ---------------------------------------------------------------------------
// Phase 1 v2: per-head M = (2+eps)*A^-1 - I,  A = (1+eps)I + (S_raw-S_raw^T).
// RANK-2 Gauss-Jordan (64 barriers).  UNCHANGED (passed twice).
// ---------------------------------------------------------------------------
__global__ __launch_bounds__(512) void cayley_invert(
    const float* __restrict__ S_raw, unsigned short* __restrict__ Mb)
{
    const int h  = blockIdx.x;
    const int t  = threadIdx.x;
    const int i  = t >> 2;      // row 0..127
    const int s  = t & 3;       // col segment 0..3
    const int j0 = s << 5;      // 32 cols per thread
    const float* Sr = S_raw + (size_t)h * 16384;

    float loc[32];
#pragma unroll
    for (int m = 0; m < 32; ++m) {
        const int j = j0 + m;
        float v = Sr[i * 128 + j] - Sr[j * 128 + i];
        if (j == i) v += 1.0f + EPSF;
        loc[m] = v;
    }

    __shared__ __align__(16) float w1buf[2][128];
    __shared__ __align__(16) float r2buf[2][128];
    __shared__ float d1buf[2][128];
    __shared__ float c2buf[2][128];

    // initial publish for pivot pair (0,1)
    if (i == 0) {
#pragma unroll
        for (int q = 0; q < 8; ++q) {
            floatx4 w;
            w[0]=loc[q*4+0]; w[1]=loc[q*4+1]; w[2]=loc[q*4+2]; w[3]=loc[q*4+3];
            if (q == 0 && s == 0) w[0] += 1.0f;
            *(floatx4*)(&w1buf[0][j0 + q*4]) = w;
        }
    }
    if (i == 1) {
#pragma unroll
        for (int q = 0; q < 8; ++q) {
            floatx4 w;
            w[0]=loc[q*4+0]; w[1]=loc[q*4+1]; w[2]=loc[q*4+2]; w[3]=loc[q*4+3];
            *(floatx4*)(&r2buf[0][j0 + q*4]) = w;
        }
    }
    if (s == 0) {
        float dv = loc[0];
        if (i == 0) dv -= 1.0f;
        d1buf[0][i] = dv;
        c2buf[0][i] = loc[1];
    }
    __syncthreads();

    for (int kb = 0; kb < 4; ++kb) {
#pragma unroll
        for (int kk = 0; kk < 16; ++kk) {         // 16 pivot-pairs per kb
            const int cur = kk & 1;
            const int nxt = cur ^ 1;
            const int k   = (kb << 5) + (kk << 1);

            const float w1k  = w1buf[cur][k];           // a_kk + 1
            const float rp1  = fast_rcp(w1k - 1.0f);    // 1/p1
            const float e1   = d1buf[cur][i] * rp1;
            const float qc   = d1buf[cur][k + 1] * rp1; // a_{k+1,k}/p1
            const float w1k1 = w1buf[cur][k + 1];       // a_{k,k+1}
            const float p2   = r2buf[cur][k + 1] - qc * w1k1;
            const float rp2  = fast_rcp(p2);
            const float c2p  = c2buf[cur][i] - e1 * w1k1;  // a'_{i,k+1}
            const float e2   = (c2p - ((i == k + 1) ? 1.0f : 0.0f)) * rp2;

            floatx4 w1v[8], r2v[8];
#pragma unroll
            for (int q = 0; q < 8; ++q) {
                w1v[q] = *(const floatx4*)(&w1buf[cur][j0 + q*4]);
                r2v[q] = *(const floatx4*)(&r2buf[cur][j0 + q*4]);
            }
#pragma unroll
            for (int m = 0; m < 32; ++m) {
                const float w1m = w1v[m >> 2][m & 3];
                const float r2p = fmaf(-qc, w1m, r2v[m >> 2][m & 3]); // w2 sans delta
                loc[m] = fmaf(-e2, r2p, fmaf(-e1, w1m, loc[m]));
            }
            if (s == kb) loc[(kk << 1) + 1] -= e2;   // delta fix at col k+1

            const int kn = k + 2;
            if (kn < 128) {
                const int sp = (kk == 15) ? kb + 1 : kb;
                const int m2 = (kk == 15) ? 0 : (kk << 1) + 2;  // col k+2 pos
                const int m3 = m2 + 1;                          // col k+3 pos
                const int q2 = m2 >> 2, f2 = m2 & 3;

                if (i == kn) {          // publish w1 = row k+2 (+1 at col k+2)
#pragma unroll
                    for (int q = 0; q < 8; ++q) {
                        floatx4 w;
                        w[0]=loc[q*4+0]; w[1]=loc[q*4+1]; w[2]=loc[q*4+2]; w[3]=loc[q*4+3];
                        if (q == q2 && s == sp) w[f2] += 1.0f;
                        *(floatx4*)(&w1buf[nxt][j0 + q*4]) = w;
                    }
                }
                if (i == kn + 1) {      // publish r2 = row k+3 raw
#pragma unroll
                    for (int q = 0; q < 8; ++q) {
                        floatx4 w;
                        w[0]=loc[q*4+0]; w[1]=loc[q*4+1]; w[2]=loc[q*4+2]; w[3]=loc[q*4+3];
                        *(floatx4*)(&r2buf[nxt][j0 + q*4]) = w;
                    }
                }
                if (s == sp) {
                    float dv = loc[m2];
                    if (i == kn) dv -= 1.0f;
                    d1buf[nxt][i] = dv;     // col k+2, -1 baked at row k+2
                    c2buf[nxt][i] = loc[m3];// col k+3 raw
                }
            }
            __syncthreads();
        }
    }

    unsigned short* dst = Mb + (size_t)h * 16384 + i * 128 + j0;
#pragma unroll
    for (int q = 0; q < 4; ++q) {
        union { shortx8 v; unsigned int u[4]; } cv;
#pragma unroll
        for (int p = 0; p < 4; ++p) {
            const int m = q*8 + p*2;
            const float v0 = (2.0f + EPSF) * loc[m]   - ((j0 + m   == i) ? 1.0f : 0.0f);
            const float v1 = (2.0f + EPSF) * loc[m+1] - ((j0 + m+1 == i) ? 1.0f : 0.0f);
            cv.u[p] = pack2_bf16(v0, v1);
        }
        *(shortx8*)(dst + q*8) = cv.v;
    }
}

// ---------------------------------------------------------------------------
// Phase 2 v7: y[n,:] = M_h @ x[n,:].  Ledger across v3..v6 (all ~86-92us):
// varied store policy (NT/plain), grid (512/2048), occupancy (8->12 w/CU),
// READ contiguity (64B sectors -> 1KB runs).  All flat at ~3.9 TB/s of
// CU<->L2 traffic (x134 + y134 + M67 MB / 86us) = 62% of copy ceiling,
// all pipes <6%.  The ONE untested config: STORE contiguity.  All versions
// scattered 64-256B chunks at 512-B row stride = every-4th-L2-line ->
// ~1/4 of L2 channels per store wave, 4x crossbar serialization; store
// backpressure throttles the whole vmem pipe (copy bench streams both
// sides).  v7: bounce acc through the free per-wave 4KB xls buffer
// (two 8-row passes, XOR-swizzled to the b128 bank floor), store as
// lane*16 -> EVERY store instr = 1KB contiguous; 4-instr group = 4KB
// stream of consecutive rows.  Reads keep v6's 1KB-contiguous pattern.
// ---------------------------------------------------------------------------
__global__ __launch_bounds__(256, 3) void cayley_apply(
    const float* __restrict__ x, const unsigned short* __restrict__ Mb,
    float* __restrict__ y)
{
    const int bid  = blockIdx.x;       // 2048 blocks
    const int bh   = bid >> 5;         // b*16+h, 0..63
    const int g    = bid & 31;         // 128-row group
    const int h    = bh & 15;
    const int tid  = threadIdx.x;
    const int w    = tid >> 6;
    const int lane = tid & 63;
    const int l15  = lane & 15;
    const int quad = lane >> 4;

    __shared__ __align__(16) unsigned short Msh[2048 * 8];   // 32768 B
    __shared__ __align__(16) unsigned char  xls[4][4096];    // 16384 B

    {   // stage M_h fragment-major: chunk c holds A-frag bytes for
        // (ct=c>>8, ks=(c>>6)&3, quad=(c>>4)&3, l15=c&15)
        const unsigned short* Mg = Mb + (size_t)h * 16384;
#pragma unroll
        for (int it = 0; it < 8; ++it) {
            const int c  = tid + it * 256;
            const int ct = c >> 8;
            const int ks = (c >> 6) & 3;
            const int qd = (c >> 4) & 3;
            const int r  = (ct << 4) | (c & 15);     // row = ct*16 + l15
            const int gq = (ks << 2) | qd;           // 16-B col chunk in row
            *(shortx8*)(&Msh[c * 8]) = *(const shortx8*)(Mg + r * 128 + gq * 8);
        }
    }
    __syncthreads();

    const size_t base = (size_t)bh * (4096 * 128);
    const int row0    = g * 128 + w * 32;            // wave's first row
    const int lrow    = lane >> 5;                   // 0..1: row within pair
    const int lcol    = (lane & 31) * 4;             // float idx within row
    const float* xw   = x + base + (size_t)(row0 + lrow) * 128 + lcol;

    unsigned char* xb = xls[w];                      // per-wave 4KB buffer
    // frag-read addresses are loop-invariant per lane
    const unsigned int rb0 = (unsigned int)l15 * 256 + (unsigned int)quad * 16;
    const unsigned int rsw = ((unsigned int)(l15 & 7)) << 4;

#pragma unroll
    for (int t = 0; t < 2; ++t) {
        const float* xt = xw + (size_t)(t * 16) * 128;

        // 8 line-contiguous loads: instr i covers rows 2i..2i+1 fully
        floatx4 xr[8];
#pragma unroll
        for (int i = 0; i < 8; ++i)
            xr[i] = *(const floatx4*)(xt + (size_t)(2 * i) * 128);
        __builtin_amdgcn_sched_barrier(0);   // keep the 8 loads batched

        // convert + swizzled LDS write (lane owns row 2i+lrow, bytes lcol*2..+8)
#pragma unroll
        for (int i = 0; i < 8; ++i) {
            const int row = 2 * i + lrow;
            const unsigned int a =
                ((unsigned int)row * 256 + (unsigned int)lcol * 2)
                ^ (((unsigned int)(row & 7)) << 4);
            uintx2 p;
            p[0] = pack2_bf16(xr[i][0], xr[i][1]);
            p[1] = pack2_bf16(xr[i][2], xr[i][3]);
            *(uintx2*)(xb + a) = p;
        }

        // same-wave DS ordering: drain writes before frag reads
        asm volatile("s_waitcnt lgkmcnt(0)" ::: "memory");
        __builtin_amdgcn_sched_barrier(0);

        shortx8 xf[4];
#pragma unroll
        for (int ks = 0; ks < 4; ++ks)
            xf[ks] = *(const shortx8*)(xb + ((rb0 + (unsigned int)ks * 64) ^ rsw));

        floatx4 acc[8];
#pragma unroll
        for (int ct = 0; ct < 8; ++ct) acc[ct] = (floatx4)0.0f;

#pragma unroll
        for (int ks = 0; ks < 4; ++ks) {
#pragma unroll
            for (int ct = 0; ct < 8; ++ct) {
                // linear wave read: addr = frag_base + lane*16 (conflict-free)
                const shortx8 mf = *(const shortx8*)(&Msh[((((ct << 2) | ks) << 6) | lane) * 8]);
                acc[ct] = __builtin_amdgcn_mfma_f32_16x16x32_bf16(mf, xf[ks], acc[ct], 0, 0, 0);
            }
        }

        // ---- epilogue v7: LDS-bounce (reuse xb) -> fully-streamed stores.
        // Two 8-row passes.  acc[ct][j] holds (n=l15, d=ct*16+quad*4+j).
        // Write pass hh: lanes with l15>>3==hh place their row rr=l15&7 at
        // obuf[rr*512 + ct*64 + quad*16] ^ (rr<<4)  (b128 bank floor).
        // Read: instr k loads obuf[k*1024 + lane*16] (unswizzled via row
        // bits) -> global store = 1KB contiguous per instr, 4KB/pass.
        char* ytb = (char*)(y + base + (size_t)(row0 + t * 16) * 128);
#pragma unroll
        for (int hh = 0; hh < 2; ++hh) {
            if ((l15 >> 3) == hh) {
                const unsigned int rr = (unsigned int)(l15 & 7);
#pragma unroll
                for (int ct = 0; ct < 8; ++ct) {
                    const unsigned int a =
                        (rr * 512u + (unsigned int)(ct * 64) + (unsigned int)(quad * 16))
                        ^ (rr << 4);
                    *(floatx4*)(xb + a) = acc[ct];
                }
            }
            asm volatile("s_waitcnt lgkmcnt(0)" ::: "memory");
            __builtin_amdgcn_sched_barrier(0);
#pragma unroll
            for (int k = 0; k < 4; ++k) {
                const unsigned int off = (unsigned int)(k * 1024) + (unsigned int)(lane * 16);
                const unsigned int a   = off ^ (((off >> 9) & 7u) << 4);
                const floatx4 v = *(const floatx4*)(xb + a);
                *(floatx4*)(ytb + (size_t)hh * 4096 + off) = v;
            }
            // reads drain before next pass / next tile reuses xb
            asm volatile("s_waitcnt lgkmcnt(0)" ::: "memory");
            __builtin_amdgcn_sched_barrier(0);
        }
    }
}

extern "C" void kernel_launch(void* const* d_in, const int* in_sizes, int n_in,
                              void* d_out, int out_size, void* d_ws, size_t ws_size,
                              hipStream_t stream) {
    const float* x     = (const float*)d_in[0];   // (4,16,4096,128) fp32
    const float* S_raw = (const float*)d_in[1];   // (16,128,128) fp32
    float* y = (float*)d_out;                     // (4,16,4096,128) fp32
    unsigned short* Mb = (unsigned short*)d_ws;   // 16*128*128 bf16 = 512 KB

    cayley_invert<<<16, 512, 0, stream>>>(S_raw, Mb);
    cayley_apply<<<64 * 32, 256, 0, stream>>>(x, Mb, y);
}